// Round 8
// baseline (351.182 us; speedup 1.0000x reference)
//
#include <hip/hip_runtime.h>

#define C_   256
#define CR_  64
#define HW_  3136
#define W_   56
#define H_   56
#define NK_  144   // K*K*G

// span_w [144][64] -> swT3 [4][64][36]: swT3[wv][rr][kk] = sw[wv*36+kk][rr]
// Per-(wv,rr) rows are 36 consecutive dwords -> s_load_dwordx16 runs. 36 864 B.
__global__ __launch_bounds__(256)
void repack_sw(const float* __restrict__ sw, float* __restrict__ swT3) {
    int idx = blockIdx.x * 256 + threadIdx.x;   // 9216 total
    int k  = idx / CR_;          // 0..143
    int rr = idx - k * CR_;      // 0..63
    int wv = k / 36, kk = k - wv * 36;
    swT3[(wv * CR_ + rr) * 36 + kk] = sw[idx];
}

// One block = 64 pixels, 4 waves, grid 1568 (6.1 blocks/CU).
// Phase A: wave wv computes r rows [wv*16,wv*16+16) over ALL 256 channels.
// Phase B: wave wv computes ker rows [wv*36,wv*36+36) (acc static-indexed).
// Phase C: wave wv handles groups [wv*4,wv*4+4) = 64 out-channels.
// ALL outer loops are runtime (#pragma unroll 1): total code ~3 KB (I$-resident).
__global__ __launch_bounds__(256, 4)
void inv_fused(const float* __restrict__ x, const float* __restrict__ rw,
               const float* __restrict__ swT3, const float* __restrict__ span_b,
               float* __restrict__ out) {
    __shared__ float rpart[CR_][64];   // [rr][pixel], 16 KiB, conflict-free

    const int b    = blockIdx.x / 49;
    const int tile = blockIdx.x % 49;
    const int wv   = threadIdx.x >> 6;
    const int lane = threadIdx.x & 63;
    const int hw   = tile * 64 + lane;
    const int h    = hw / W_;
    const int w    = hw - h * W_;
    const float* xb = x + (size_t)b * C_ * HW_;

    const int rr0 = __builtin_amdgcn_readfirstlane(wv * 16);

    // ---------- phase A: 16 r-rows over 256 channels, reg-double-buffered x ----------
    float racc[16];
    #pragma unroll
    for (int j = 0; j < 16; ++j) racc[j] = 0.f;

    float xv[8];
    #pragma unroll
    for (int u = 0; u < 8; ++u) xv[u] = xb[(size_t)u * HW_ + hw];

    #pragma unroll 1                                    // RUNTIME loop: tiny code
    for (int i = 0; i < C_; i += 8) {
        float xn[8];
        if (i + 8 < C_) {                               // uniform branch
            #pragma unroll
            for (int u = 0; u < 8; ++u)                 // next tile in flight
                xn[u] = xb[(size_t)(i + 8 + u) * HW_ + hw];
        }
        #pragma unroll
        for (int j = 0; j < 16; ++j) {
            const float* wr = rw + (size_t)(rr0 + j) * C_ + i;  // uniform -> s_load_x8
            #pragma unroll
            for (int u = 0; u < 8; ++u)
                racc[j] += wr[u] * xv[u];               // v_fmac, SGPR weight operand
        }
        #pragma unroll
        for (int u = 0; u < 8; ++u) xv[u] = xn[u];
    }
    #pragma unroll
    for (int j = 0; j < 16; ++j)
        rpart[rr0 + j][lane] = racc[j];
    __syncthreads();

    // ---------- phase B: ker[36] = swT3[wv] . r + b (static acc, runtime rr) ----------
    const int k0 = __builtin_amdgcn_readfirstlane(wv * 36);
    float acc[36];
    #pragma unroll
    for (int k = 0; k < 36; ++k) acc[k] = span_b[k0 + k];

    const float* swv = swT3 + (size_t)wv * CR_ * 36;    // uniform base
    #pragma unroll 1                                    // RUNTIME loop
    for (int rr = 0; rr < CR_; ++rr) {
        const float rv = rpart[rr][lane];               // 1 ds_read_b32
        const float* wr = swv + rr * 36;                // uniform, 36 consecutive dwords
        #pragma unroll
        for (int k = 0; k < 36; ++k)                    // STATIC acc index
            acc[k] += wr[k] * rv;
    }

    // ---------- phase C: 9-tap involution, 4 groups (64 channels) ----------
    const bool hok0 = (h > 0), hok2 = (h < H_ - 1);
    const bool wok0 = (w > 0), wok2 = (w < W_ - 1);

    #pragma unroll 1                                    // RUNTIME loop
    for (int cg = 0; cg < 16; ++cg) {
        #pragma unroll
        for (int gi = 0; gi < 4; ++gi) {                // static: acc[gi*9+k]
            const int c = wv * 64 + gi * 16 + cg;
            const float* xc = xb + (size_t)c * HW_ + hw;
            float a = 0.f;
            #pragma unroll
            for (int k = 0; k < 9; ++k) {
                const int di = k / 3 - 1, dj = k % 3 - 1;
                const bool ok = (di < 0 ? hok0 : (di > 0 ? hok2 : true))
                             && (dj < 0 ? wok0 : (dj > 0 ? wok2 : true));
                if (ok) a += acc[gi * 9 + k] * xc[di * W_ + dj];
            }
            out[((size_t)b * C_ + c) * HW_ + hw] = a;   // coalesced store
        }
    }
}

extern "C" void kernel_launch(void* const* d_in, const int* in_sizes, int n_in,
                              void* d_out, int out_size, void* d_ws, size_t ws_size,
                              hipStream_t stream) {
    const float* x  = (const float*)d_in[0];
    const float* rw = (const float*)d_in[1];  // [64][256]
    const float* sw = (const float*)d_in[2];  // [144][64]
    const float* sb = (const float*)d_in[3];  // [144]
    float* out  = (float*)d_out;
    float* swT3 = (float*)d_ws;               // 36 864 B

    repack_sw<<<36, 256, 0, stream>>>(sw, swT3);
    inv_fused<<<16 * 49, 256, 0, stream>>>(x, rw, swT3, sb, out);
}

// Round 11
// 260.314 us; speedup vs baseline: 1.3491x; 1.3491x over previous
//
#include <hip/hip_runtime.h>

#define C_   256
#define CR_  64
#define HW_  3136
#define W_   56
#define H_   56
#define NK_  144
#define PADK 150   // kerlds row stride (bf16 elems): 75 dwords, gcd(75,32)=1 -> 2-way (free)

typedef __attribute__((ext_vector_type(4))) float f32x4;
typedef __attribute__((ext_vector_type(8))) short bf16x8;

__device__ __forceinline__ unsigned short f2b(float f) {   // fp32 -> bf16 RNE
    union { float f; unsigned u; } v; v.f = f;
    unsigned r = v.u + 0x7fffu + ((v.u >> 16) & 1u);
    return (unsigned short)(r >> 16);
}
__device__ __forceinline__ float b2f(unsigned short s) {
    union { unsigned u; float f; } v; v.u = ((unsigned)s) << 16;
    return v.f;
}

// weights fp32 -> bf16 copies in d_ws (rwb 32 KiB @0, swb 18 KiB @32K; total 50 KiB)
__global__ __launch_bounds__(256)
void prep(const float* __restrict__ rw, const float* __restrict__ sw,
          unsigned short* __restrict__ rwb, unsigned short* __restrict__ swb) {
    int t = blockIdx.x * 256 + threadIdx.x;
    if (t < CR_ * C_)  rwb[t] = f2b(rw[t]);
    if (t < NK_ * CR_) swb[t] = f2b(sw[t]);
}

// Block = 64 pixels, 4 waves. GEMM-1: R[64rr,64px]=RW*X (MFMA, wave=16 M-rows).
// GEMM-2: KER[144,64px]=SW*R (MFMA, wave=16 px, 9 M-tiles). Phase C: 9-tap fp32.
__global__ __launch_bounds__(256, 4)
void inv_mfma(const float* __restrict__ x, const unsigned short* __restrict__ rwb,
              const unsigned short* __restrict__ swb, const float* __restrict__ span_b,
              float* __restrict__ out) {
    __shared__ __align__(16) unsigned char smem[8192 + 32768]; // rlds | xlds/kerlds

    const int b    = blockIdx.x / 49;
    const int tile = blockIdx.x % 49;
    const int wv   = threadIdx.x >> 6;
    const int lane = threadIdx.x & 63;
    const int hw0  = tile * 64;
    const int hw   = hw0 + lane;
    const int h    = hw / W_;
    const int w    = hw - h * W_;
    const int l15  = lane & 15;
    const int lq   = lane >> 4;
    const float* xb = x + (size_t)b * C_ * HW_;

    // ---- stage x-tile -> xlds bf16 [px][c], XOR-swizzled (G4) ----
    {
        char* xlds = (char*)smem + 8192;
        const int cb = wv * 64;                       // this wave's 64 channels
        #pragma unroll 2
        for (int u = 0; u < 8; ++u) {
            float v[8];
            #pragma unroll
            for (int j = 0; j < 8; ++j)
                v[j] = xb[(size_t)(cb + u * 8 + j) * HW_ + hw];  // coalesced 256B/wave
            uint4 pk;
            pk.x = f2b(v[0]) | ((unsigned)f2b(v[1]) << 16);
            pk.y = f2b(v[2]) | ((unsigned)f2b(v[3]) << 16);
            pk.z = f2b(v[4]) | ((unsigned)f2b(v[5]) << 16);
            pk.w = f2b(v[6]) | ((unsigned)f2b(v[7]) << 16);
            *(uint4*)(xlds + lane * 512 + (((cb + u * 8) * 2) ^ ((lane & 7) << 4))) = pk;
        }
    }
    __syncthreads();

    // ---- GEMM-1: R rows [wv*16,wv*16+16) x 64 px, K=256 (8 k-steps) ----
    f32x4 acc[4];
    #pragma unroll
    for (int nt = 0; nt < 4; ++nt) acc[nt] = f32x4{0.f, 0.f, 0.f, 0.f};
    {
        bf16x8 afr[8];                                 // A = RW, preloaded (vector, pipelined)
        const unsigned short* arow = rwb + (wv * 16 + l15) * C_ + lq * 8;
        #pragma unroll
        for (int kk = 0; kk < 8; ++kk)
            afr[kk] = *(const bf16x8*)(arow + kk * 32);

        char* xlds = (char*)smem + 8192;
        #pragma unroll
        for (int nt = 0; nt < 4; ++nt) {
            const int bpx = nt * 16 + l15;
            #pragma unroll
            for (int kk = 0; kk < 8; ++kk) {
                bf16x8 bfr = *(const bf16x8*)(xlds + bpx * 512 +
                                ((kk * 64 + lq * 16) ^ ((bpx & 7) << 4)));
                acc[nt] = __builtin_amdgcn_mfma_f32_16x16x32_bf16(afr[kk], bfr, acc[nt], 0, 0, 0);
            }
        }
    }
    // ---- R -> rlds bf16 [px][rr], XOR-swizzled ----
    {
        char* rlds = (char*)smem;
        #pragma unroll
        for (int nt = 0; nt < 4; ++nt) {
            const int ppx = nt * 16 + l15;             // D: col=lane&15
            const int rr  = wv * 16 + lq * 4;          // D: row=(lane>>4)*4+reg
            unsigned lo = f2b(acc[nt][0]) | ((unsigned)f2b(acc[nt][1]) << 16);
            unsigned hi = f2b(acc[nt][2]) | ((unsigned)f2b(acc[nt][3]) << 16);
            char* p = rlds + ppx * 128 + ((rr * 2) ^ ((ppx & 7) << 4));
            *(unsigned*)(p)     = lo;
            *(unsigned*)(p + 4) = hi;
        }
    }
    __syncthreads();

    // ---- GEMM-2: KER[144, px-tile wv] = SW * R, K=64 (2 k-steps) ----
    f32x4 acc2[9];
    #pragma unroll
    for (int mt = 0; mt < 9; ++mt) acc2[mt] = f32x4{0.f, 0.f, 0.f, 0.f};
    {
        char* rlds = (char*)smem;
        const int ppx = wv * 16 + l15;
        bf16x8 b0 = *(const bf16x8*)(rlds + ppx * 128 + ((lq * 16)      ^ ((ppx & 7) << 4)));
        bf16x8 b1 = *(const bf16x8*)(rlds + ppx * 128 + ((64 + lq * 16) ^ ((ppx & 7) << 4)));
        const unsigned short* sbase = swb + l15 * CR_ + lq * 8;
        #pragma unroll
        for (int mt = 0; mt < 9; ++mt) {
            bf16x8 a0 = *(const bf16x8*)(sbase + mt * 16 * CR_);
            bf16x8 a1 = *(const bf16x8*)(sbase + mt * 16 * CR_ + 32);
            acc2[mt] = __builtin_amdgcn_mfma_f32_16x16x32_bf16(a0, b0, acc2[mt], 0, 0, 0);
            acc2[mt] = __builtin_amdgcn_mfma_f32_16x16x32_bf16(a1, b1, acc2[mt], 0, 0, 0);
        }
    }
    // ---- bias + KER -> kerlds bf16 [px][PADK] (reuses xlds region) ----
    {
        char* kerlds = (char*)smem + 8192;
        const int ppx = wv * 16 + l15;
        #pragma unroll
        for (int mt = 0; mt < 9; ++mt) {
            const int kb = mt * 16 + lq * 4;
            unsigned lo = f2b(acc2[mt][0] + span_b[kb])     | ((unsigned)f2b(acc2[mt][1] + span_b[kb + 1]) << 16);
            unsigned hi = f2b(acc2[mt][2] + span_b[kb + 2]) | ((unsigned)f2b(acc2[mt][3] + span_b[kb + 3]) << 16);
            char* p = kerlds + ppx * (PADK * 2) + kb * 2;
            *(unsigned*)(p)     = lo;
            *(unsigned*)(p + 4) = hi;
        }
    }
    __syncthreads();

    // ---- phase C: 9-tap involution, wave wv -> channels [wv*64, wv*64+64) ----
    {
        const char* kerlds = (const char*)smem + 8192;
        float ker9[4][9];
        #pragma unroll
        for (int gi = 0; gi < 4; ++gi)
            #pragma unroll
            for (int j = 0; j < 9; ++j)
                ker9[gi][j] = b2f(*(const unsigned short*)(kerlds + lane * (PADK * 2)
                                    + ((wv * 4 + gi) * 9 + j) * 2));

        const bool hok0 = (h > 0), hok2 = (h < H_ - 1);
        const bool wok0 = (w > 0), wok2 = (w < W_ - 1);

        #pragma unroll 2
        for (int cg = 0; cg < 16; ++cg) {
            #pragma unroll
            for (int gi = 0; gi < 4; ++gi) {
                const int c = wv * 64 + gi * 16 + cg;
                const float* xc = xb + (size_t)c * HW_ + hw;
                float a = 0.f;
                #pragma unroll
                for (int k = 0; k < 9; ++k) {
                    const int di = k / 3 - 1, dj = k % 3 - 1;
                    const bool ok = (di < 0 ? hok0 : (di > 0 ? hok2 : true))
                                 && (dj < 0 ? wok0 : (dj > 0 ? wok2 : true));
                    if (ok) a += ker9[gi][k] * xc[di * W_ + dj];
                }
                out[((size_t)b * C_ + c) * HW_ + hw] = a;
            }
        }
    }
}

extern "C" void kernel_launch(void* const* d_in, const int* in_sizes, int n_in,
                              void* d_out, int out_size, void* d_ws, size_t ws_size,
                              hipStream_t stream) {
    const float* x  = (const float*)d_in[0];
    const float* rw = (const float*)d_in[1];  // [64][256]
    const float* sw = (const float*)d_in[2];  // [144][64]
    const float* sb = (const float*)d_in[3];  // [144]
    float* out = (float*)d_out;
    unsigned short* rwb = (unsigned short*)d_ws;            // 32768 B
    unsigned short* swb = (unsigned short*)((char*)d_ws + 32768); // 18432 B

    prep<<<64, 256, 0, stream>>>(rw, sw, rwb, swb);
    inv_mfma<<<16 * 49, 256, 0, stream>>>(x, rwb, swb, sb, out);
}